// Round 13
// baseline (28.065 us; speedup 1.0000x reference)
//
#include <hip/hip_runtime.h>
#include <math.h>
#include <stdint.h>

#define BATCH 32
#define ND 512
#define NC 100
#define BIGNEG 1000000.0f

__device__ __forceinline__ float rdlane_f(float v, int t) {
  return __uint_as_float(__builtin_amdgcn_readlane(__float_as_uint(v), (uint32_t)t));
}

// y one-hot => only column j* = label survives the -BIG masks:
// out[b] = max_i  bu_i - BIG*y_i - bl_j* + 0.5*(Du_i - dq + A_i)
// 256 blocks = 32 b x 8 nq (64 n each); the 8th finisher per batch does the
// epilogue in-kernel (hipCUB last-block pattern) -> single kernel dispatch.
__global__ __launch_bounds__(256, 8) void adv_all(
    const float* __restrict__ z, const float* __restrict__ wu,
    const float* __restrict__ wl, const float* __restrict__ bu,
    const float* __restrict__ bl, const float* __restrict__ y,
    float* __restrict__ P, int* __restrict__ cnt, float* __restrict__ out)
{
  // XCD-chunk swizzle; id>>5 is constant for a batch's 8 blocks -> same XCD (heuristic)
  const int id = ((blockIdx.x & 7) << 5) + (blockIdx.x >> 3);
  const int b = id >> 3, nq = id & 7;
  const int tid = threadIdx.x;
  const int wv = tid >> 6, l = tid & 63;
  const int ns = wv & 1, ih = wv >> 1;   // n-subchunk of 32, i-half of 64

  __shared__ int s_js, s_last;
  __shared__ float s_dq[2];
  __shared__ float s_p[128];
  __shared__ float s_mx[2];

  if (tid == 0) s_js = 0;
  __syncthreads();
  if (tid < NC && y[b * NC + tid] > 0.5f) s_js = tid;   // one-hot -> single writer
  __syncthreads();
  const int js = s_js;

  const int n0 = (nq << 6) + (ns << 5);
  const int nl = n0 + (l & 31);          // lanes 32..63 duplicate lanes 0..31
  const float* zb = z + (size_t)b * 2 * ND;
  const float zlo = zb[nl], zhi = zb[ND + nl];
  const float cc = zlo + zhi;            // 2*center
  const float rr = zhi - zlo;            // 2*radius >= 0
  const float qv = wl[((size_t)b * ND + nl) * NC + js];

  if (ih == 0) {                          // dq partial: sum over lanes 0..31
    float p = cc * qv;
#pragma unroll
    for (int off = 1; off < 32; off <<= 1) p += __shfl_xor(p, off, 64);
    if (l == 0) s_dq[ns] = p;
  }

  const int i  = (ih << 6) + l;
  const int iL = (i < NC) ? i : NC - 1;
  const float* up = wu + ((size_t)b * ND + n0) * NC + iL;

  float amp = 0.f, dot = 0.f;
#pragma unroll
  for (int t = 0; t < 32; ++t) {
    float u  = up[(size_t)t * NC];       // coalesced, L2-resident
    float cs = rdlane_f(cc, t);
    float rs = rdlane_f(rr, t);
    float qs = rdlane_f(qv, t);
    float d  = u - qs;
    amp = fmaf(rs, fabsf(d), amp);
    dot = fmaf(cs, u, dot);
  }
  const float v = amp + dot;
  if (ns == 1) s_p[i] = v;
  __syncthreads();
  if (ns == 0)
    P[(size_t)id * 128 + i] = v + s_p[i] - (s_dq[0] + s_dq[1]);
  __threadfence();                        // make P row device-visible
  __syncthreads();                        // all writes fenced before the ticket
  if (tid == 0) s_last = (atomicAdd(&cnt[b], 1) == 7);
  __syncthreads();
  if (!s_last) return;

  // ---- last arriving block of batch b: epilogue ----
  float m = -INFINITY;
  if (tid < 128) {
    const float* pb = P + ((size_t)(b << 3)) * 128 + tid;
    float s = 0.f;
#pragma unroll
    for (int q = 0; q < 8; ++q)
      s += __hip_atomic_load(pb + (q << 7), __ATOMIC_RELAXED, __HIP_MEMORY_SCOPE_AGENT);
    if (tid < NC)
      m = bu[b * NC + tid] - BIGNEG * y[b * NC + tid] - bl[b * NC + js] + 0.5f * s;
  }
#pragma unroll
  for (int off = 32; off; off >>= 1) m = fmaxf(m, __shfl_down(m, off, 64));
  if (tid < 128 && (tid & 63) == 0) s_mx[tid >> 6] = m;
  __syncthreads();
  if (tid == 0) {
    out[b] = fmaxf(s_mx[0], s_mx[1]);
    cnt[b] = 0;                           // self-reset: replays start clean
  }
}

extern "C" void kernel_launch(void* const* d_in, const int* in_sizes, int n_in,
                              void* d_out, int out_size, void* d_ws, size_t ws_size,
                              hipStream_t stream) {
  // inputs: 0:x (unused), 1:z_tensor, 2:w_u, 3:b_u, 4:w_l, 5:b_l, 6:y_tensor
  const float* z  = (const float*)d_in[1];
  const float* wu = (const float*)d_in[2];
  const float* bu = (const float*)d_in[3];
  const float* wl = (const float*)d_in[4];
  const float* bl = (const float*)d_in[5];
  const float* y  = (const float*)d_in[6];

  int*   cnt = (int*)d_ws;                          // 32 counters
  float* P   = (float*)((char*)d_ws + 512);         // 256 x 128 floats = 128 KB

  hipMemsetAsync(cnt, 0, BATCH * sizeof(int), stream);   // poison-proof counters
  adv_all<<<BATCH * 8, 256, 0, stream>>>(z, wu, wl, bu, bl, y, P, cnt, (float*)d_out);
}

// Round 14
// 11.787 us; speedup vs baseline: 2.3810x; 2.3810x over previous
//
#include <hip/hip_runtime.h>
#include <math.h>
#include <stdint.h>

#define BATCH 32
#define ND 512
#define NC 100
#define NQ 8            // n-chunks of 64
#define BIGNEG 1000000.0f

__device__ __forceinline__ float rdlane_f(float v, int t) {
  return __uint_as_float(__builtin_amdgcn_readlane(__float_as_uint(v), (uint32_t)t));
}

// y is one-hot: b_f's -BIG masks kill all (i,j) except j = j* (label), i != j*.
// out[b] = max_i  bu_i - BIG*y_i - bl_j* + 0.5*(Du_i - dq + A_i)
//   Du_i = sum_n cc_n*wu[n][i],  dq = sum_n cc_n*wl[n][j*],
//   A_i  = sum_n rr_n*|wu[n][i]-wl[n][j*]|,  cc = lo+hi, rr = hi-lo.
// Partial kernel: 256 blocks = 32 b x 8 nq (64 n each) -> 1 block/CU.
__global__ __launch_bounds__(128, 8) void adv_part(
    const float* __restrict__ z, const float* __restrict__ wu,
    const float* __restrict__ wl, const float* __restrict__ y,
    float* __restrict__ P)
{
  // XCD-chunk swizzle (256 = 8*32, bijective), b-major -> 4 batches per XCD
  const int id = ((blockIdx.x & 7) << 5) + (blockIdx.x >> 3);
  const int b = id >> 3, nq = id & 7;
  const int tid  = threadIdx.x;
  const int half = tid >> 6, l = tid & 63;

  __shared__ int   s_js;
  __shared__ float s_dq;

  if (tid == 0) s_js = 0;
  __syncthreads();
  if (tid < NC && y[b * NC + tid] > 0.5f) s_js = tid;
  __syncthreads();
  const int js = s_js;

  // lane l holds n = nq*64 + l's cc/rr/q (both waves load the same values)
  const int n0 = nq << 6;
  const int n  = n0 + l;
  const float* zb = z + (size_t)b * 2 * ND;
  const float zlo = zb[n], zhi = zb[ND + n];
  const float cc = zlo + zhi;
  const float rr = zhi - zlo;           // >= 0
  const float qv = wl[((size_t)b * ND + n) * NC + js];

  if (half == 0) {                       // dq partial for this n-chunk
    float p = cc * qv;
#pragma unroll
    for (int off = 1; off < 64; off <<= 1) p += __shfl_xor(p, off, 64);
    if (l == 0) s_dq = p;
  }

  const int i  = (half << 6) + l;
  const int iL = (i < NC) ? i : NC - 1;
  const float* up = wu + ((size_t)b * ND + n0) * NC + iL;

  float amp = 0.f, dotu = 0.f;
#pragma unroll 16
  for (int t = 0; t < 64; ++t) {
    float u  = up[(size_t)t * NC];      // coalesced, L2/HBM pipelined
    float cs = rdlane_f(cc, t);
    float rs = rdlane_f(rr, t);
    float qs = rdlane_f(qv, t);
    float d  = u - qs;
    amp  = fmaf(rs, fabsf(d), amp);
    dotu = fmaf(cs, u, dotu);
  }
  __syncthreads();
  P[(size_t)id * 128 + tid] = amp + dotu - s_dq;
}

__global__ __launch_bounds__(128) void adv_fin(
    const float* __restrict__ P, const float* __restrict__ bu,
    const float* __restrict__ bl, const float* __restrict__ y,
    float* __restrict__ out)
{
  const int b = blockIdx.x, tid = threadIdx.x;
  __shared__ int   s_js;
  __shared__ float s_mx[2];

  if (tid == 0) s_js = 0;
  __syncthreads();
  if (tid < NC && y[b * NC + tid] > 0.5f) s_js = tid;
  __syncthreads();
  const int js = s_js;

  float m = -INFINITY;
  if (tid < NC) {
    const float* pb = P + ((size_t)b * NQ) * 128 + tid;
    float s = 0.f;
#pragma unroll
    for (int q = 0; q < NQ; ++q) s += pb[q * 128];   // coalesced, L2-resident
    m = bu[b * NC + tid] - BIGNEG * y[b * NC + tid] - bl[b * NC + js] + 0.5f * s;
  }
#pragma unroll
  for (int off = 32; off; off >>= 1) m = fmaxf(m, __shfl_down(m, off, 64));
  if ((tid & 63) == 0) s_mx[tid >> 6] = m;
  __syncthreads();
  if (tid == 0) out[b] = fmaxf(s_mx[0], s_mx[1]);
}

extern "C" void kernel_launch(void* const* d_in, const int* in_sizes, int n_in,
                              void* d_out, int out_size, void* d_ws, size_t ws_size,
                              hipStream_t stream) {
  // inputs: 0:x (unused), 1:z_tensor, 2:w_u, 3:b_u, 4:w_l, 5:b_l, 6:y_tensor
  const float* z  = (const float*)d_in[1];
  const float* wu = (const float*)d_in[2];
  const float* bu = (const float*)d_in[3];
  const float* wl = (const float*)d_in[4];
  const float* bl = (const float*)d_in[5];
  const float* y  = (const float*)d_in[6];
  float* P = (float*)d_ws;    // 256 * 128 floats = 128 KB

  adv_part<<<BATCH * NQ, 128, 0, stream>>>(z, wu, wl, y, P);
  adv_fin<<<BATCH, 128, 0, stream>>>(P, bu, bl, y, (float*)d_out);
}